// Round 2
// baseline (232.174 us; speedup 1.0000x reference)
//
#include <hip/hip_runtime.h>
#include <hip/hip_bf16.h>
#include <stdint.h>

// Problem constants (from reference setup_inputs)
#define BB 64
#define SS 2048
#define DD 6
#define HH 8
#define NCH 512           // chains = B*H
#define CHUNKS 256        // chunks per chain
#define LCH 8             // steps per chunk = SS/CHUNKS

// ---------------- compile-time Cayley sign table (Cl(4,1)) ----------------
struct SignTab { float s[32][32]; };

constexpr int popc5_c(unsigned v) {
    int c = 0;
    for (int i = 0; i < 5; ++i) c += (v >> i) & 1u;
    return c;
}

constexpr SignTab make_signs() {
    SignTab t{};
    for (int a = 0; a < 32; ++a) {
        for (int b = 0; b < 32; ++b) {
            int cnt = 0;
            unsigned aa = ((unsigned)a) >> 1;
            while (aa) { cnt += popc5_c(aa & (unsigned)b); aa >>= 1; }
            if ((a & b) & 16) cnt += 1;   // metric: e5^2 = -1 (bit 4)
            t.s[a][b] = (cnt & 1) ? -1.0f : 1.0f;
        }
    }
    return t;
}

constexpr SignTab SGN = make_signs();

// out = a * b  (geometric product, a is LEFT operand: out_k = sum_i s(i,i^k) a_i b_{i^k})
__device__ __forceinline__ void gp_cl41(const float* __restrict__ a,
                                        const float* __restrict__ b,
                                        float* __restrict__ o) {
#pragma unroll
    for (int k = 0; k < 32; ++k) o[k] = 0.0f;
#pragma unroll
    for (int i = 0; i < 32; ++i) {
#pragma unroll
        for (int k = 0; k < 32; ++k) {
            o[k] = fmaf(SGN.s[i][i ^ k] * a[i], b[i ^ k], o[k]);
        }
    }
}

__device__ __forceinline__ float sumsq32(const float* v) {
    float n0 = 0.f, n1 = 0.f, n2 = 0.f, n3 = 0.f;
#pragma unroll
    for (int k = 0; k < 32; k += 4) {
        n0 = fmaf(v[k+0], v[k+0], n0);
        n1 = fmaf(v[k+1], v[k+1], n1);
        n2 = fmaf(v[k+2], v[k+2], n2);
        n3 = fmaf(v[k+3], v[k+3], n3);
    }
    return (n0 + n1) + (n2 + n3);
}

__device__ __forceinline__ float rsq(float n) {
    return __builtin_amdgcn_rsqf(n);   // v_rsq_f32, ~1e-7 rel err, scale-equivalent
}

__device__ __forceinline__ void norm32(float* v) {
    float inv = rsq(sumsq32(v));
#pragma unroll
    for (int k = 0; k < 32; ++k) v[k] *= inv;
}

__device__ __forceinline__ uint32_t f2bf_rne(float f) {
    uint32_t u = __float_as_uint(f);
    return (u + 0x7FFFu + ((u >> 16) & 1u)) >> 16;
}

// ---------------- K1: per-chunk sequential totals (unnormalized chain) ----------------
// tid = c*512 + b*8 + h ; each thread does LCH sequential GP steps from identity.
// All normalize() calls are positive rescales -> deferred to the chunk end.
// Range: |delta| <= ~5.7, GP growth <= sqrt(32) -> |p| <= ~1e12 worst over 8 steps; safe in fp32.
__global__ __launch_bounds__(256) void k_chunk_totals(
        const float* __restrict__ x, const float* __restrict__ W_in,
        const float* __restrict__ b_in, float* __restrict__ Tbuf) {
    __shared__ float sW[8][228];   // per h: 192 W + 32 bias, stride 228 (bank-stagger)
    for (int idx = threadIdx.x; idx < 8 * 224; idx += 256) {
        int h = idx / 224, r = idx % 224;
        float v;
        if (r < 192) { int d = r / 32, j = r % 32; v = W_in[d * 256 + h * 32 + j]; }
        else         { int j = r - 192;            v = b_in[h * 32 + j]; }
        sW[h][r] = v;
    }
    __syncthreads();

    int tid = blockIdx.x * 256 + threadIdx.x;
    int c  = tid >> 9;
    int bh = tid & 511;
    int b = bh >> 3, h = bh & 7;

    float p[32];
#pragma unroll
    for (int k = 0; k < 32; ++k) p[k] = 0.f;
    p[0] = 1.f;

    const float* xrow = x + ((size_t)b * SS + (size_t)c * LCH) * DD;
#pragma unroll 1
    for (int r = 0; r < LCH; ++r) {
        float xv[6];
#pragma unroll
        for (int d = 0; d < 6; ++d) xv[d] = xrow[d];
        xrow += 6;
        float dl[32];
#pragma unroll
        for (int j = 0; j < 32; ++j) dl[j] = sW[h][192 + j];
#pragma unroll
        for (int d = 0; d < 6; ++d)
#pragma unroll
            for (int j = 0; j < 32; ++j)
                dl[j] = fmaf(xv[d], sW[h][d * 32 + j], dl[j]);
        dl[0] += 1.0f;
        // no delta normalize, no psi normalize: pure positive scales, deferred

        float o[32];
        gp_cl41(dl, p, o);   // newer delta on the LEFT
#pragma unroll
        for (int k = 0; k < 32; ++k) p[k] = o[k];
    }

    norm32(p);               // single rescale for the whole chunk
    float* dst = Tbuf + ((size_t)bh * CHUNKS + c) * 32;
#pragma unroll
    for (int k = 0; k < 32; ++k) dst[k] = p[k];
}

// ---------------- K2: Kogge-Stone scan of chunk totals per chain ----------------
// Per-round normalize kept: Kogge-Stone doubles log-magnitude per round ->
// unnormalized values would overflow fp32 doubly-exponentially.
__global__ __launch_bounds__(256) void k_scan_totals(
        const float* __restrict__ Tbuf, float* __restrict__ Ebuf) {
    __shared__ float sT[CHUNKS][33];   // +1 pad to kill bank conflicts (33.8 KB)
    int chain = blockIdx.x;            // 0..511
    int c = threadIdx.x;               // 0..255

    float v[32];
    const float* src = Tbuf + ((size_t)chain * CHUNKS + c) * 32;
#pragma unroll
    for (int k = 0; k < 32; ++k) { v[k] = src[k]; sT[c][k] = v[k]; }
    __syncthreads();

#pragma unroll 1
    for (int off = 1; off < CHUNKS; off <<= 1) {
        float w[32];
        bool act = (c >= off);
        if (act) {
#pragma unroll
            for (int k = 0; k < 32; ++k) w[k] = sT[c - off][k];
        }
        __syncthreads();
        if (act) {
            float o[32];
            gp_cl41(v, w, o);          // v covers newer range -> left
            norm32(o);
#pragma unroll
            for (int k = 0; k < 32; ++k) { v[k] = o[k]; sT[c][k] = v[k]; }
        }
        __syncthreads();
    }

    // exclusive carries: E_0 = identity, E_{c+1} = inclusive_c
    // NOTE: Ebuf may alias Tbuf — all Tbuf reads completed before first barrier,
    // and blocks touch disjoint chain regions.
    float* dst = Ebuf + (size_t)chain * CHUNKS * 32;
    if (c == 0) {
#pragma unroll
        for (int k = 0; k < 32; ++k) dst[k] = (k == 0) ? 1.f : 0.f;
    }
    if (c < CHUNKS - 1) {
        float* d2 = dst + (size_t)(c + 1) * 32;
#pragma unroll
        for (int k = 0; k < 32; ++k) d2[k] = v[k];
    }
}

// ---------------- K3: re-run chunks seeded with carry, emit psi (bf16) ----------------
// Chain kept UNNORMALIZED (rsq only feeds the store -> off the serial critical path).
__global__ __launch_bounds__(256) void k_scan_apply(
        const float* __restrict__ x, const float* __restrict__ W_in,
        const float* __restrict__ b_in, const float* __restrict__ Ebuf,
        __hip_bfloat16* __restrict__ psi_buf) {
    __shared__ float sW[8][228];
    for (int idx = threadIdx.x; idx < 8 * 224; idx += 256) {
        int h = idx / 224, r = idx % 224;
        float v;
        if (r < 192) { int d = r / 32, j = r % 32; v = W_in[d * 256 + h * 32 + j]; }
        else         { int j = r - 192;            v = b_in[h * 32 + j]; }
        sW[h][r] = v;
    }
    __syncthreads();

    int tid = blockIdx.x * 256 + threadIdx.x;
    int c  = tid >> 9;
    int bh = tid & 511;
    int b = bh >> 3, h = bh & 7;

    float p[32];
    const float* e = Ebuf + ((size_t)bh * CHUNKS + c) * 32;
#pragma unroll
    for (int k = 0; k < 32; ++k) p[k] = e[k];

    const float* xrow = x + ((size_t)b * SS + (size_t)c * LCH) * DD;
#pragma unroll 1
    for (int r = 0; r < LCH; ++r) {
        float xv[6];
#pragma unroll
        for (int d = 0; d < 6; ++d) xv[d] = xrow[d];
        xrow += 6;
        float dl[32];
#pragma unroll
        for (int j = 0; j < 32; ++j) dl[j] = sW[h][192 + j];
#pragma unroll
        for (int d = 0; d < 6; ++d)
#pragma unroll
            for (int j = 0; j < 32; ++j)
                dl[j] = fmaf(xv[d], sW[h][d * 32 + j], dl[j]);
        dl[0] += 1.0f;
        // delta NOT normalized (scale-equivalent; absorbed by the store rescale)

        float o[32];
        gp_cl41(dl, p, o);
#pragma unroll
        for (int k = 0; k < 32; ++k) p[k] = o[k];   // chain stays unnormalized

        // store psi_t = p * rsqrt(|p|^2) as bf16 at (b, t, h, :)
        float inv = rsq(sumsq32(p));
        int t = c * LCH + r;
        __hip_bfloat16* dst = psi_buf + (((size_t)b * SS + t) * HH + h) * 32;
        uint32_t pk[16];
#pragma unroll
        for (int m = 0; m < 16; ++m) {
            uint32_t lo = f2bf_rne(p[2 * m] * inv);
            uint32_t hi = f2bf_rne(p[2 * m + 1] * inv);
            pk[m] = lo | (hi << 16);
        }
        uint4* d4 = (uint4*)dst;   // 64B aligned
#pragma unroll
        for (int m = 0; m < 4; ++m) {
            d4[m] = make_uint4(pk[4*m], pk[4*m+1], pk[4*m+2], pk[4*m+3]);
        }
    }
}

// ---------------- K4: output projection 256->32 + normalize ----------------
__global__ __launch_bounds__(256) void k_proj(
        const __hip_bfloat16* __restrict__ psi_buf, const float* __restrict__ W_out,
        const float* __restrict__ b_out, float* __restrict__ out) {
    __shared__ float sWo[256 * 32];   // 32 KB
    __shared__ float sB[32];
    for (int idx = threadIdx.x; idx < 256 * 32; idx += 256) sWo[idx] = W_out[idx];
    if (threadIdx.x < 32) sB[threadIdx.x] = b_out[threadIdx.x];
    __syncthreads();

    int row = blockIdx.x * 256 + threadIdx.x;   // (b*S + s), 0..131071
    float acc[32];
#pragma unroll
    for (int o = 0; o < 32; ++o) acc[o] = sB[o];

    const uint4* prow = (const uint4*)(psi_buf + (size_t)row * 256);
#pragma unroll 4
    for (int g = 0; g < 32; ++g) {
        uint4 q = prow[g];
        uint32_t wz[4] = { q.x, q.y, q.z, q.w };
#pragma unroll
        for (int m = 0; m < 4; ++m) {
            float f0 = __uint_as_float(wz[m] << 16);
            float f1 = __uint_as_float(wz[m] & 0xFFFF0000u);
            int j = g * 8 + m * 2;
#pragma unroll
            for (int o = 0; o < 32; ++o) acc[o] = fmaf(f0, sWo[j * 32 + o], acc[o]);
#pragma unroll
            for (int o = 0; o < 32; ++o) acc[o] = fmaf(f1, sWo[(j + 1) * 32 + o], acc[o]);
        }
    }

    float inv = rsq(sumsq32(acc));
    float* orow = out + (size_t)row * 32;
#pragma unroll
    for (int o = 0; o < 32; ++o) orow[o] = acc[o] * inv;
}

// ---------------- launcher ----------------
extern "C" void kernel_launch(void* const* d_in, const int* in_sizes, int n_in,
                              void* d_out, int out_size, void* d_ws, size_t ws_size,
                              hipStream_t stream) {
    const float* x     = (const float*)d_in[0];
    const float* W_in  = (const float*)d_in[1];
    const float* b_in  = (const float*)d_in[2];
    const float* W_out = (const float*)d_in[3];
    const float* b_out = (const float*)d_in[4];
    float* out = (float*)d_out;

    char* ws = (char*)d_ws;
    float* Tbuf = (float*)ws;                                   // 512*256*32*4 = 16 MB
    float* Ebuf = Tbuf;                                         // aliased (safe, see K2)
    __hip_bfloat16* psi = (__hip_bfloat16*)(ws + (size_t)16 * 1024 * 1024); // 64 MB

    k_chunk_totals<<<512, 256, 0, stream>>>(x, W_in, b_in, Tbuf);
    k_scan_totals <<<512, 256, 0, stream>>>(Tbuf, Ebuf);
    k_scan_apply  <<<512, 256, 0, stream>>>(x, W_in, b_in, Ebuf, psi);
    k_proj        <<<512, 256, 0, stream>>>(psi, W_out, b_out, out);
}

// Round 4
// 197.540 us; speedup vs baseline: 1.1753x; 1.1753x over previous
//
#include <hip/hip_runtime.h>
#include <hip/hip_bf16.h>
#include <stdint.h>

// Problem constants (from reference setup_inputs)
#define BB 64
#define SS 2048
#define DD 6
#define HH 8
#define NCH 512           // chains = B*H
#define CHUNKS 256        // chunks per chain
#define LCH 8             // steps per chunk = SS/CHUNKS

typedef unsigned short ushort_t;
typedef __attribute__((ext_vector_type(8))) __bf16 bf16x8;
typedef __attribute__((ext_vector_type(4))) float f32x4;

// ---------------- compile-time Cayley sign table (Cl(4,1)) ----------------
struct SignTab { float s[32][32]; };

constexpr int popc5_c(unsigned v) {
    int c = 0;
    for (int i = 0; i < 5; ++i) c += (v >> i) & 1u;
    return c;
}

constexpr SignTab make_signs() {
    SignTab t{};
    for (int a = 0; a < 32; ++a) {
        for (int b = 0; b < 32; ++b) {
            int cnt = 0;
            unsigned aa = ((unsigned)a) >> 1;
            while (aa) { cnt += popc5_c(aa & (unsigned)b); aa >>= 1; }
            if ((a & b) & 16) cnt += 1;   // metric: e5^2 = -1 (bit 4)
            t.s[a][b] = (cnt & 1) ? -1.0f : 1.0f;
        }
    }
    return t;
}

constexpr SignTab SGN = make_signs();

// out = a * b  (geometric product, a is LEFT operand: out_k = sum_i s(i,i^k) a_i b_{i^k})
__device__ __forceinline__ void gp_cl41(const float* __restrict__ a,
                                        const float* __restrict__ b,
                                        float* __restrict__ o) {
#pragma unroll
    for (int k = 0; k < 32; ++k) o[k] = 0.0f;
#pragma unroll
    for (int i = 0; i < 32; ++i) {
#pragma unroll
        for (int k = 0; k < 32; ++k) {
            o[k] = fmaf(SGN.s[i][i ^ k] * a[i], b[i ^ k], o[k]);
        }
    }
}

__device__ __forceinline__ float sumsq32(const float* v) {
    float n0 = 0.f, n1 = 0.f, n2 = 0.f, n3 = 0.f;
#pragma unroll
    for (int k = 0; k < 32; k += 4) {
        n0 = fmaf(v[k+0], v[k+0], n0);
        n1 = fmaf(v[k+1], v[k+1], n1);
        n2 = fmaf(v[k+2], v[k+2], n2);
        n3 = fmaf(v[k+3], v[k+3], n3);
    }
    return (n0 + n1) + (n2 + n3);
}

__device__ __forceinline__ float rsq(float n) {
    return __builtin_amdgcn_rsqf(n);   // v_rsq_f32, scale-equivalent
}

__device__ __forceinline__ uint32_t f2bf_rne(float f) {
    uint32_t u = __float_as_uint(f);
    return (u + 0x7FFFu + ((u >> 16) & 1u)) >> 16;
}

// fp16 pack/unpack (RNE via _Float16 cast); psi components are unit-bounded -> safe
__device__ __forceinline__ uint32_t packh2(float a, float b) {
    union { _Float16 h[2]; uint32_t u; } t;
    t.h[0] = (_Float16)a; t.h[1] = (_Float16)b;
    return t.u;
}
__device__ __forceinline__ float h2lo(uint32_t u) {
    union { uint32_t u32; _Float16 h[2]; } t; t.u32 = u; return (float)t.h[0];
}
__device__ __forceinline__ float h2hi(uint32_t u) {
    union { uint32_t u32; _Float16 h[2]; } t; t.u32 = u; return (float)t.h[1];
}

// ---------------- K1: fused delta-compute + chunk-local prefix ----------------
// thread (c, bh): 8 sequential steps from identity (UNNORMALIZED chain; all
// normalize() in the reference are positive rescales -> scale-equivalent).
// Emits: psi_loc[t] = normalized local prefix (FP16 — bf16 was too coarse: its
// quantization feeds the fixup GP and amplified to 0.038 absmax), Tbuf = fp32 total.
// Deltas computed in PAIRS so each W element is LDS-read once per 2 steps.
__global__ __launch_bounds__(256) void k_local(
        const float* __restrict__ x, const float* __restrict__ W_in,
        const float* __restrict__ b_in, ushort_t* __restrict__ psi_loc,
        float* __restrict__ Tbuf) {
    // sW4[h][d*8 + j4] = W_in[d][h*32 + 4*j4 .. +4); [h][48..55] = bias
    __shared__ float4 sW4[8][57];
    for (int idx = threadIdx.x; idx < 8 * 56; idx += 256) {
        int h = idx / 56, r = idx % 56;
        float4 v;
        if (r < 48) {
            int d = r / 8, j4 = r % 8;
            const float* p = W_in + d * 256 + h * 32 + 4 * j4;
            v = make_float4(p[0], p[1], p[2], p[3]);
        } else {
            const float* p = b_in + h * 32 + 4 * (r - 48);
            v = make_float4(p[0], p[1], p[2], p[3]);
        }
        sW4[h][r] = v;
    }
    __syncthreads();

    int tid = blockIdx.x * 256 + threadIdx.x;
    int c  = tid >> 9;
    int bh = tid & 511;
    int b = bh >> 3, h = bh & 7;

    float4 bias4[8];
#pragma unroll
    for (int j4 = 0; j4 < 8; ++j4) bias4[j4] = sW4[h][48 + j4];

    float p[32];
#pragma unroll
    for (int k = 0; k < 32; ++k) p[k] = 0.f;
    p[0] = 1.f;

    const float* xrow = x + ((size_t)b * SS + (size_t)c * LCH) * DD;
    ushort_t* psi_base = psi_loc + (((size_t)b * SS + (size_t)c * LCH) * HH + h) * 32;

#pragma unroll 1
    for (int pr = 0; pr < LCH / 2; ++pr) {
        // 12 contiguous x floats = two steps' inputs (8B aligned)
        float xv[12];
#pragma unroll
        for (int d = 0; d < 6; ++d) {
            float2 t2 = *(const float2*)(xrow + 2 * d);
            xv[2 * d] = t2.x; xv[2 * d + 1] = t2.y;
        }
        xrow += 12;
        float x0[6], x1[6];
#pragma unroll
        for (int d = 0; d < 6; ++d) { x0[d] = xv[d]; x1[d] = xv[6 + d]; }

        float dl0[32], dl1[32];
#pragma unroll
        for (int j4 = 0; j4 < 8; ++j4) {
            float4 bv = bias4[j4];
            dl0[4*j4+0] = bv.x; dl0[4*j4+1] = bv.y; dl0[4*j4+2] = bv.z; dl0[4*j4+3] = bv.w;
            dl1[4*j4+0] = bv.x; dl1[4*j4+1] = bv.y; dl1[4*j4+2] = bv.z; dl1[4*j4+3] = bv.w;
        }
#pragma unroll
        for (int d = 0; d < 6; ++d) {
            float a0 = x0[d], a1 = x1[d];
#pragma unroll
            for (int j4 = 0; j4 < 8; ++j4) {
                float4 w = sW4[h][d * 8 + j4];   // one LDS read serves both steps
                dl0[4*j4+0] = fmaf(a0, w.x, dl0[4*j4+0]);
                dl0[4*j4+1] = fmaf(a0, w.y, dl0[4*j4+1]);
                dl0[4*j4+2] = fmaf(a0, w.z, dl0[4*j4+2]);
                dl0[4*j4+3] = fmaf(a0, w.w, dl0[4*j4+3]);
                dl1[4*j4+0] = fmaf(a1, w.x, dl1[4*j4+0]);
                dl1[4*j4+1] = fmaf(a1, w.y, dl1[4*j4+1]);
                dl1[4*j4+2] = fmaf(a1, w.z, dl1[4*j4+2]);
                dl1[4*j4+3] = fmaf(a1, w.w, dl1[4*j4+3]);
            }
        }
        dl0[0] += 1.0f;
        dl1[0] += 1.0f;

        float o[32];
        gp_cl41(dl0, p, o);   // step 2*pr (newer delta LEFT); chain unnormalized
        {
            float inv = rsq(sumsq32(o));
            ushort_t* dst = psi_base + (size_t)(2 * pr) * HH * 32;
            uint32_t pk[16];
#pragma unroll
            for (int m = 0; m < 16; ++m)
                pk[m] = packh2(o[2*m] * inv, o[2*m+1] * inv);
            uint4* d4 = (uint4*)dst;
#pragma unroll
            for (int m = 0; m < 4; ++m)
                d4[m] = make_uint4(pk[4*m], pk[4*m+1], pk[4*m+2], pk[4*m+3]);
        }
        gp_cl41(dl1, o, p);   // step 2*pr+1
        {
            float inv = rsq(sumsq32(p));
            ushort_t* dst = psi_base + (size_t)(2 * pr + 1) * HH * 32;
            uint32_t pk[16];
#pragma unroll
            for (int m = 0; m < 16; ++m)
                pk[m] = packh2(p[2*m] * inv, p[2*m+1] * inv);
            uint4* d4 = (uint4*)dst;
#pragma unroll
            for (int m = 0; m < 4; ++m)
                d4[m] = make_uint4(pk[4*m], pk[4*m+1], pk[4*m+2], pk[4*m+3]);
        }
    }

    // chunk total, normalized fp32
    float inv = rsq(sumsq32(p));
    float* dst = Tbuf + ((size_t)bh * CHUNKS + c) * 32;
#pragma unroll
    for (int k = 0; k < 32; ++k) dst[k] = p[k] * inv;
}

// ---------------- K2: Kogge-Stone scan of chunk totals per chain ----------------
__global__ __launch_bounds__(256) void k_scan_totals(
        const float* __restrict__ Tbuf, float* __restrict__ Ebuf) {
    __shared__ float sT[CHUNKS][33];
    int chain = blockIdx.x;            // 0..511
    int c = threadIdx.x;               // 0..255

    float v[32];
    const float* src = Tbuf + ((size_t)chain * CHUNKS + c) * 32;
#pragma unroll
    for (int k = 0; k < 32; ++k) { v[k] = src[k]; sT[c][k] = v[k]; }
    __syncthreads();

#pragma unroll 1
    for (int off = 1; off < CHUNKS; off <<= 1) {
        float w[32];
        bool act = (c >= off);
        if (act) {
#pragma unroll
            for (int k = 0; k < 32; ++k) w[k] = sT[c - off][k];
        }
        __syncthreads();
        if (act) {
            float o[32];
            gp_cl41(v, w, o);          // v covers newer range -> left
            float inv = rsq(sumsq32(o));
#pragma unroll
            for (int k = 0; k < 32; ++k) { v[k] = o[k] * inv; sT[c][k] = v[k]; }
        }
        __syncthreads();
    }

    // exclusive carries: E_0 = identity, E_{c+1} = inclusive_c (Ebuf may alias Tbuf)
    float* dst = Ebuf + (size_t)chain * CHUNKS * 32;
    if (c == 0) {
#pragma unroll
        for (int k = 0; k < 32; ++k) dst[k] = (k == 0) ? 1.f : 0.f;
    }
    if (c < CHUNKS - 1) {
        float* d2 = dst + (size_t)(c + 1) * 32;
#pragma unroll
        for (int k = 0; k < 32; ++k) d2[k] = v[k];
    }
}

// ---------------- K3: fused fixup (GP with carry) + MFMA projection + norm ----------------
__global__ __launch_bounds__(256) void k_fixup_proj(
        const ushort_t* __restrict__ psi_loc, const float* __restrict__ Ebuf,
        const float* __restrict__ W_out, const float* __restrict__ b_out,
        float* __restrict__ out) {
    int lane = threadIdx.x & 63;
    int wv = threadIdx.x >> 6;
    int q = lane >> 4;          // quad id 0..3
    int n0 = lane & 15;         // output column within 16-tile

    // B-fragments in registers: B[k][n], k = kk*32 + q*8 + j, n = nt*16 + n0
    bf16x8 Bf[2][8];
#pragma unroll
    for (int nt = 0; nt < 2; ++nt)
#pragma unroll
        for (int kk = 0; kk < 8; ++kk) {
            union { ushort_t u[8]; bf16x8 v; } tmp;
#pragma unroll
            for (int j = 0; j < 8; ++j)
                tmp.u[j] = (ushort_t)f2bf_rne(W_out[(kk * 32 + q * 8 + j) * 32 + nt * 16 + n0]);
            Bf[nt][kk] = tmp.v;
        }
    float bn0 = b_out[n0], bn1 = b_out[16 + n0];

    __shared__ ushort_t psiT[4][16][264];   // 16 rows x 256 bf16 (+8 pad) per wave

#pragma unroll 1
    for (int tile = blockIdx.x * 4 + wv; tile < 8192; tile += 2048) {
        int rr0 = tile * 16;
        int b = rr0 >> 11;                  // 16-row tiles never straddle b
        int s0 = rr0 & 2047;

        __syncthreads();                    // psiT safe to overwrite

        // fixup: 128 (row,h) pairs -> 2 per lane
#pragma unroll
        for (int pp = 0; pp < 2; ++pp) {
            int row_local = pp * 8 + (lane >> 3);
            int h = lane & 7;
            int s = s0 + row_local;
            int c = s >> 3;
            int bh = b * 8 + h;

            // load local psi (fp16) and carry (fp32)
            float a[32], w[32], o[32];
            const uint4* pl = (const uint4*)(psi_loc +
                    (((size_t)b * SS + s) * HH + h) * 32);
#pragma unroll
            for (int m = 0; m < 4; ++m) {
                uint4 t4 = pl[m];
                uint32_t uu[4] = { t4.x, t4.y, t4.z, t4.w };
#pragma unroll
                for (int z = 0; z < 4; ++z) {
                    a[8*m + 2*z]     = h2lo(uu[z]);
                    a[8*m + 2*z + 1] = h2hi(uu[z]);
                }
            }
            const float* e = Ebuf + ((size_t)bh * CHUNKS + c) * 32;
#pragma unroll
            for (int k = 0; k < 32; ++k) w[k] = e[k];

            gp_cl41(a, w, o);               // local (newer) LEFT x carry
            float inv = rsq(sumsq32(o));

            uint32_t pk[16];
#pragma unroll
            for (int m = 0; m < 16; ++m)
                pk[m] = f2bf_rne(o[2*m] * inv) | (f2bf_rne(o[2*m+1] * inv) << 16);
            uint4* dst = (uint4*)&psiT[wv][row_local][h * 32];
#pragma unroll
            for (int m = 0; m < 4; ++m)
                dst[m] = make_uint4(pk[4*m], pk[4*m+1], pk[4*m+2], pk[4*m+3]);
        }

        __syncthreads();                    // wave-aligned; makes psiT visible

        // projection: 16x256 @ 256x32 via 16 MFMAs
        f32x4 acc0 = {0.f, 0.f, 0.f, 0.f};
        f32x4 acc1 = {0.f, 0.f, 0.f, 0.f};
#pragma unroll
        for (int kk = 0; kk < 8; ++kk) {
            // A-frag: A[m=lane&15][k=kk*32+q*8+j]
            bf16x8 af = *(const bf16x8*)&psiT[wv][n0][kk * 32 + q * 8];
            acc0 = __builtin_amdgcn_mfma_f32_16x16x32_bf16(af, Bf[0][kk], acc0, 0, 0, 0);
            acc1 = __builtin_amdgcn_mfma_f32_16x16x32_bf16(af, Bf[1][kk], acc1, 0, 0, 0);
        }

        // epilogue: bias, row-norm across 32 cols (16 lanes x 2), store
        float c0[4], c1[4], ss[4];
#pragma unroll
        for (int i = 0; i < 4; ++i) {
            c0[i] = acc0[i] + bn0;
            c1[i] = acc1[i] + bn1;
            ss[i] = c0[i] * c0[i] + c1[i] * c1[i];
        }
#pragma unroll
        for (int m = 1; m < 16; m <<= 1) {
#pragma unroll
            for (int i = 0; i < 4; ++i) ss[i] += __shfl_xor(ss[i], m);
        }
#pragma unroll
        for (int i = 0; i < 4; ++i) {
            float inv = rsq(ss[i]);
            int row = rr0 + q * 4 + i;
            out[(size_t)row * 32 + n0]      = c0[i] * inv;
            out[(size_t)row * 32 + 16 + n0] = c1[i] * inv;
        }
    }
}

// ---------------- launcher ----------------
extern "C" void kernel_launch(void* const* d_in, const int* in_sizes, int n_in,
                              void* d_out, int out_size, void* d_ws, size_t ws_size,
                              hipStream_t stream) {
    const float* x     = (const float*)d_in[0];
    const float* W_in  = (const float*)d_in[1];
    const float* b_in  = (const float*)d_in[2];
    const float* W_out = (const float*)d_in[3];
    const float* b_out = (const float*)d_in[4];
    float* out = (float*)d_out;

    char* ws = (char*)d_ws;
    float* Tbuf = (float*)ws;                                   // 512*256*32*4 = 16 MB
    float* Ebuf = Tbuf;                                         // aliased (safe, see K2)
    ushort_t* psi = (ushort_t*)(ws + (size_t)16 * 1024 * 1024); // 64 MB fp16 local prefixes

    k_local      <<<512, 256, 0, stream>>>(x, W_in, b_in, psi, Tbuf);
    k_scan_totals<<<512, 256, 0, stream>>>(Tbuf, Ebuf);
    k_fixup_proj <<<512, 256, 0, stream>>>(psi, Ebuf, W_out, b_out, out);
}